// Round 1
// 669.984 us; speedup vs baseline: 1.5426x; 1.5426x over previous
//
#include <hip/hip_runtime.h>
#include <hip/hip_bf16.h>
#include <math.h>

#define NB 64
#define C1n 4096
#define C2n 128
#define DIMH 512
#define HIDN 516
#define INPN 132
#define EPSF 1e-8f

typedef __hip_bfloat16 bf16;

// workspace layout (float offsets)
enum : size_t {
  OFF_SKC = 0,          // 64   (zero-init)
  OFF_SKX = 64,         // 64   (zero-init)
  OFF_RX  = 128,        // 8192 (zero-init)
  ZERO_FLOATS = 8320,   // memset range
  OFF_K   = 8320,       // 8192
  OFF_INVNK = 16512,    // 64
  OFF_BETA  = 16576,    // 64
  OFF_FLAG  = 16640,    // 64 (probe: 1.0 => inputs are f32, 0.0 => bf16)
  OFF_EKC = 16704,      // 262144
  OFF_EKX = 278848,     // 262144
  OFF_WB  = 540992,     // 1048576 (w_bias, [n][c][4])
  OFF_RB  = 1589568,    // 256
  OFF_SR  = 1589824,    // 33024
  OFF_SZ  = 1622848,    // 33024
  OFF_SNI = 1655872,    // 33024
  OFF_SNH = 1688896,    // 33024
  OFF_E   = 1721920,    // 8192
  OFF_V   = 1730112,    // 8192
  OFF_HOB = 1738304,    // 256
  WS_FLOATS = 1738560   // ~6.95 MB
};

__device__ __forceinline__ float ldf(const void* p, size_t i, int f){
  if(f) return ((const float*)p)[i];
  return __bfloat162float(((const bf16*)p)[i]);
}
__device__ __forceinline__ void stf(void* p, size_t i, float v, int f){
  if(f) ((float*)p)[i] = v;
  else  ((bf16*)p)[i] = __float2bfloat16(v);
}
// vectorized 4-element load/store (ei must be a multiple of 4)
__device__ __forceinline__ float4 ld4(const void* p, size_t ei, int f){
  if(f) return ((const float4*)p)[ei >> 2];
  union { ushort4 u; bf16 h[4]; } t;
  t.u = ((const ushort4*)p)[ei >> 2];
  return make_float4(__bfloat162float(t.h[0]), __bfloat162float(t.h[1]),
                     __bfloat162float(t.h[2]), __bfloat162float(t.h[3]));
}
__device__ __forceinline__ void st4(void* p, size_t ei, float4 v, int f){
  if(f){ ((float4*)p)[ei >> 2] = v; return; }
  union { ushort4 u; bf16 h[4]; } t;
  t.h[0] = __float2bfloat16(v.x); t.h[1] = __float2bfloat16(v.y);
  t.h[2] = __float2bfloat16(v.z); t.h[3] = __float2bfloat16(v.w);
  ((ushort4*)p)[ei >> 2] = t.u;
}
__device__ __forceinline__ float expc(float x){
  return expf(fminf(fmaxf(x, -60.f), 60.f));
}

// ---------------- K0: dtype probe ----------------
__global__ void k0_probe(const void* cp, float* __restrict__ ws){
  int t = threadIdx.x; // 256
  __shared__ float red[256];
  const bf16* p = (const bf16*)cp;
  float m = 0.f;
  for(int i = t; i < 8192; i += 256){
    float v = __bfloat162float(p[i]);
    if(v != v) v = 1e30f;           // NaN -> huge
    m = fmaxf(m, fabsf(v));
  }
  red[t] = m;
  __syncthreads();
  for(int s = 128; s; s >>= 1){
    if(t < s) red[t] = fmaxf(red[t], red[t + s]);
    __syncthreads();
  }
  if(t == 0) ws[OFF_FLAG] = (red[0] > 1e4f) ? 1.0f : 0.0f;
}

// ---------------- K1: k = origin_h @ Wk^T + bk ; beta ; 1/||k|| ----------------
__global__ void k1_kbeta(const void* hop, const void* Wk, const void* bk,
                         const void* Wb, const void* bb, float* __restrict__ ws){
  int n = blockIdx.x;
  int t = threadIdx.x; // 256
  int f = (ws[OFF_FLAG] != 0.f);
  __shared__ float h[DIMH];
  __shared__ float kk[C2n];
  for(int d = t; d < DIMH; d += 256) h[d] = ldf(hop, (size_t)n*HIDN + d, f);
  __syncthreads();
  if(t < C2n){
    float acc = 0.f;
    for(int d = 0; d < DIMH; ++d) acc += h[d] * ldf(Wk, (size_t)t*DIMH + d, f);
    acc += ldf(bk, t, f);
    kk[t] = acc;
    ws[OFF_K + n*C2n + t] = acc;
  } else if(t == 128){
    float acc = 0.f;
    for(int d = 0; d < DIMH; ++d) acc += h[d] * ldf(Wb, d, f);
    acc += ldf(bb, 0, f);
    float sp = fmaxf(acc, 0.f) + log1pf(expc(-fabsf(acc)));  // softplus
    ws[OFF_BETA + n] = sp + 1.0f;
  }
  __syncthreads();
  if(t == 0){
    float s = 0.f;
    for(int c = 0; c < C2n; ++c) s += kk[c]*kk[c];
    ws[OFF_INVNK + n] = 1.0f / fmaxf(sqrtf(s), EPSF);
  }
}

// ---------------- K2: cos-sims, exp weights, sums, fused rx accumulation ----------
// Coalesced: one half-wave (32 lanes x float4) owns each 512B row. Butterfly
// reductions (xor masks 1..16 stay within each 32-lane half, so a wave reduces
// 2 rows concurrently). c_xf float4 stays in registers -> rx fused, read once.
__global__ void k2_score(const void* cp, const void* cx, float* __restrict__ ws){
  int n = blockIdx.y;
  int cbase = blockIdx.x * 256;   // grid.x = 16
  int t = threadIdx.x;            // 256 = 4 waves
  int f = (ws[OFF_FLAG] != 0.f);
  int wave = t >> 6;
  int lane = t & 63;
  int half = lane >> 5;           // half-wave id within wave
  int l = lane & 31;              // lane within half

  // k fragment in registers: lane l covers d = 4l..4l+3
  float k0 = ws[OFF_K + n*C2n + l*4 + 0];
  float k1 = ws[OFF_K + n*C2n + l*4 + 1];
  float k2 = ws[OFF_K + n*C2n + l*4 + 2];
  float k3 = ws[OFF_K + n*C2n + l*4 + 3];
  float beta  = ws[OFF_BETA + n];
  float invnk = ws[OFF_INVNK + n];

  float sA = 0.f, sB = 0.f;
  float r0 = 0.f, r1 = 0.f, r2 = 0.f, r3 = 0.f;

  for(int it = 0; it < 32; ++it){
    int row = cbase + it*8 + wave*2 + half;   // 8 consecutive rows / block-iter
    size_t base = ((size_t)n*C1n + row)*C2n + l*4;
    float4 a = ld4(cp, base, f);
    float4 b = ld4(cx, base, f);

    float dc = a.x*k0 + a.y*k1 + a.z*k2 + a.w*k3;
    float nc = a.x*a.x + a.y*a.y + a.z*a.z + a.w*a.w;
    float dx = b.x*k0 + b.y*k1 + b.z*k2 + b.w*k3;
    float nx = b.x*b.x + b.y*b.y + b.z*b.z + b.w*b.w;
    #pragma unroll
    for(int m = 1; m < 32; m <<= 1){
      dc += __shfl_xor(dc, m, 64);
      nc += __shfl_xor(nc, m, 64);
      dx += __shfl_xor(dx, m, 64);
      nx += __shfl_xor(nx, m, 64);
    }
    float skc = dc / fmaxf(sqrtf(nc), EPSF) * invnk;
    float skx = dx / fmaxf(sqrtf(nx), EPSF) * invnk;
    float ekc = expc(skc * beta);   // |beta*s| small: unnormalized softmax safe
    float ekx = expc(skx * beta);
    if(l == 0){
      ws[OFF_EKC + (size_t)n*C1n + row] = ekc;
      ws[OFF_EKX + (size_t)n*C1n + row] = ekx;
    }
    sA += ekc; sB += ekx;
    // fused rx: lane l owns d = 4l..4l+3 of this row's c_xf (still in regs)
    r0 += ekx*b.x; r1 += ekx*b.y; r2 += ekx*b.z; r3 += ekx*b.w;
  }

  // combine the two half-waves (lane l and l^32 hold the same d slots)
  r0 += __shfl_xor(r0, 32, 64);
  r1 += __shfl_xor(r1, 32, 64);
  r2 += __shfl_xor(r2, 32, 64);
  r3 += __shfl_xor(r3, 32, 64);
  sA += __shfl_xor(sA, 32, 64);
  sB += __shfl_xor(sB, 32, 64);

  __shared__ float rxw[4][C2n];
  __shared__ float sred[8];
  if(lane < 32){
    rxw[wave][l*4 + 0] = r0; rxw[wave][l*4 + 1] = r1;
    rxw[wave][l*4 + 2] = r2; rxw[wave][l*4 + 3] = r3;
  }
  if(lane == 0){ sred[wave] = sA; sred[4 + wave] = sB; }
  __syncthreads();
  if(t < C2n)
    atomicAdd(&ws[OFF_RX + n*C2n + t],
              rxw[0][t] + rxw[1][t] + rxw[2][t] + rxw[3][t]);
  if(t == 0) atomicAdd(&ws[OFF_SKC + n], sred[0]+sred[1]+sred[2]+sred[3]);
  if(t == 1) atomicAdd(&ws[OFF_SKX + n], sred[4]+sred[5]+sred[6]+sred[7]);
}

// ---------------- K3a: w_bias (roll + softmax over 4 shifts), rb ----------------
__global__ void k3a_wbias(float* __restrict__ ws){
  int n = blockIdx.x;
  int t = threadIdx.x; // 256
  __shared__ float wl[C1n]; // 16KB
  __shared__ float r0[256], r1[256], r2[256], r3[256];
  float invSc = 1.0f / fmaxf(ws[OFF_SKC + n], 1e-30f);
  float invSx = 1.0f / fmaxf(ws[OFF_SKX + n], 1e-30f);
  for(int c = t; c < C1n; c += 256) wl[c] = ws[OFF_EKC + n*C1n + c] * invSc;
  __syncthreads();
  float a0=0.f, a1=0.f, a2=0.f, a3=0.f;
  for(int c = t; c < C1n; c += 256){
    int x = c >> 6, y = c & 63;
    // SHIFTS=((0,1),(1,0),(0,-1),(-1,0)): rolled[x,y]=w[(x-sx)&63,(y-sy)&63]
    float w0 = wl[ (x << 6)            | ((y-1) & 63) ];
    float w1 = wl[ (((x-1) & 63) << 6) | y            ];
    float w2 = wl[ (x << 6)            | ((y+1) & 63) ];
    float w3 = wl[ (((x+1) & 63) << 6) | y            ];
    float m = fmaxf(fmaxf(w0,w1), fmaxf(w2,w3));
    float e0 = expc(w0-m), e1 = expc(w1-m), e2 = expc(w2-m), e3 = expc(w3-m);
    float inv = 1.0f/(e0+e1+e2+e3);
    e0 *= inv; e1 *= inv; e2 *= inv; e3 *= inv;
    size_t wb = OFF_WB + ((size_t)n*C1n + c)*4;
    ws[wb] = e0; ws[wb+1] = e1; ws[wb+2] = e2; ws[wb+3] = e3;
    float wx = ws[OFF_EKX + n*C1n + c] * invSx;
    a0 += wx*e0; a1 += wx*e1; a2 += wx*e2; a3 += wx*e3;
  }
  r0[t]=a0; r1[t]=a1; r2[t]=a2; r3[t]=a3;
  __syncthreads();
  for(int s = 128; s; s >>= 1){
    if(t < s){ r0[t]+=r0[t+s]; r1[t]+=r1[t+s]; r2[t]+=r2[t+s]; r3[t]+=r3[t+s]; }
    __syncthreads();
  }
  if(t == 0){
    ws[OFF_RB + n*4 + 0] = r0[0]; ws[OFF_RB + n*4 + 1] = r1[0];
    ws[OFF_RB + n*4 + 2] = r2[0]; ws[OFF_RB + n*4 + 3] = r3[0];
  }
}

// ---------------- K3b: GRU gate GEMVs (4 kinds) ----------------
__global__ void k3b_gates(const void* hop, const void* Wih, const void* Whh,
                          const void* bih, const void* bhh, float* __restrict__ ws){
  int n = blockIdx.x, g = blockIdx.y;
  int t = threadIdx.x; // 576
  int f = (ws[OFF_FLAG] != 0.f);
  __shared__ float x[INPN];
  __shared__ float h[HIDN];
  if(t < INPN){
    float v;
    if(t < C2n) v = ws[OFF_RX + n*C2n + t] / fmaxf(ws[OFF_SKX + n], 1e-30f);
    else        v = ws[OFF_RB + n*4 + (t - C2n)];
    x[t] = v;
  }
  for(int d = t; d < HIDN; d += 576) h[d] = ldf(hop, (size_t)n*HIDN + d, f);
  __syncthreads();
  if(t < HIDN){
    int j = t;
    float acc = 0.f;
    if(g <= 1){
      int row = g*HIDN + j;
      for(int d = 0; d < INPN; ++d) acc += x[d] * ldf(Wih, (size_t)row*INPN + d, f);
      for(int d = 0; d < HIDN; ++d) acc += h[d] * ldf(Whh, (size_t)row*HIDN + d, f);
      acc += ldf(bih, row, f) + ldf(bhh, row, f);
      ws[(g == 0 ? OFF_SR : OFF_SZ) + n*HIDN + j] = acc;
    } else if(g == 2){
      int row = 2*HIDN + j;
      for(int d = 0; d < INPN; ++d) acc += x[d] * ldf(Wih, (size_t)row*INPN + d, f);
      acc += ldf(bih, row, f);
      ws[OFF_SNI + n*HIDN + j] = acc;
    } else {
      int row = 2*HIDN + j;
      for(int d = 0; d < HIDN; ++d) acc += h[d] * ldf(Whh, (size_t)row*HIDN + d, f);
      acc += ldf(bhh, row, f);
      ws[OFF_SNH + n*HIDN + j] = acc;
    }
  }
}

// ---------------- K3c: GRU combine, h_o out, h_o_bias, e, v ----------------
__global__ void k3c_combine(const void* hop, const void* We, const void* be,
                            const void* Wv, const void* bv,
                            float* __restrict__ ws, void* out){
  int n = blockIdx.x;
  int t = threadIdx.x; // 576
  int f = (ws[OFF_FLAG] != 0.f);
  __shared__ float ho[HIDN];
  if(t < HIDN){
    float sr = ws[OFF_SR  + n*HIDN + t];
    float sz = ws[OFF_SZ  + n*HIDN + t];
    float si = ws[OFF_SNI + n*HIDN + t];
    float sh = ws[OFF_SNH + n*HIDN + t];
    float rg = 1.0f/(1.0f + expc(-sr));
    float zg = 1.0f/(1.0f + expc(-sz));
    float ng = tanhf(si + rg*sh);
    float hv = ldf(hop, (size_t)n*HIDN + t, f);
    float o = (1.0f - zg)*ng + zg*hv;
    ho[t] = o;
    stf(out, (size_t)n*HIDN + t, o, f);
  }
  __syncthreads();
  if(t == 0){
    float a = ho[512], b = ho[513], c = ho[514], d2 = ho[515];
    float m = fmaxf(fmaxf(a,b), fmaxf(c,d2));
    float e0 = expc(a-m), e1 = expc(b-m), e2 = expc(c-m), e3 = expc(d2-m);
    float inv = 1.0f/(e0+e1+e2+e3);
    ws[OFF_HOB + n*4 + 0] = e0*inv; ws[OFF_HOB + n*4 + 1] = e1*inv;
    ws[OFF_HOB + n*4 + 2] = e2*inv; ws[OFF_HOB + n*4 + 3] = e3*inv;
  }
  if(t < 256){
    int c2 = t & 127, sel = t >> 7;
    const void* W = sel ? Wv : We;
    float acc = 0.f;
    for(int d = 0; d < DIMH; ++d) acc += ho[d] * ldf(W, (size_t)c2*DIMH + d, f);
    if(sel) ws[OFF_V + n*C2n + c2] = acc + ldf(bv, c2, f);
    else {
      float e = acc + ldf(be, c2, f);
      ws[OFF_E + n*C2n + c2] = 1.0f/(1.0f + expc(-e));
    }
  }
}

// ---------------- K4: c_new = c_prev*(1 - w_kc*e) + w_write*v (float4) ----------
__global__ void k4_cnew(const void* cp, float* __restrict__ ws, void* out){
  int n = blockIdx.y;
  int cbase = blockIdx.x * 128;
  int t = threadIdx.x; // 256: 32 float4-lanes x 8 channels in flight
  int f = (ws[OFF_FLAG] != 0.f);
  int dq = t & 31, sub = t >> 5;
  int d0 = dq * 4;
  float invSc = 1.0f / fmaxf(ws[OFF_SKC + n], 1e-30f);
  float4 ed = *(const float4*)&ws[OFF_E + n*C2n + d0];
  float4 vd = *(const float4*)&ws[OFF_V + n*C2n + d0];
  float h0 = ws[OFF_HOB + n*4 + 0], h1 = ws[OFF_HOB + n*4 + 1];
  float h2 = ws[OFF_HOB + n*4 + 2], h3 = ws[OFF_HOB + n*4 + 3];
  for(int i = 0; i < 16; ++i){
    int c = cbase + i*8 + sub;
    float wkc = ws[OFF_EKC + (size_t)n*C1n + c] * invSc;
    float4 wb4 = *(const float4*)&ws[OFF_WB + ((size_t)n*C1n + c)*4];
    float wwr = wb4.x*h0 + wb4.y*h1 + wb4.z*h2 + wb4.w*h3;
    size_t idx = ((size_t)n*C1n + c)*C2n + d0;
    float4 a = ld4(cp, idx, f);
    float4 o;
    o.x = a.x*(1.0f - wkc*ed.x) + wwr*vd.x;
    o.y = a.y*(1.0f - wkc*ed.y) + wwr*vd.y;
    o.z = a.z*(1.0f - wkc*ed.z) + wwr*vd.z;
    o.w = a.w*(1.0f - wkc*ed.w) + wwr*vd.w;
    st4(out, (size_t)(NB*HIDN) + idx, o, f);
  }
}

extern "C" void kernel_launch(void* const* d_in, const int* in_sizes, int n_in,
                              void* d_out, int out_size, void* d_ws, size_t ws_size,
                              hipStream_t stream){
  const void* hop = d_in[0];
  const void* cp  = d_in[1];
  const void* cx  = d_in[2];
  const void* Wk  = d_in[3];
  const void* bk  = d_in[4];
  const void* Wb  = d_in[5];
  const void* bb  = d_in[6];
  const void* We  = d_in[7];
  const void* be  = d_in[8];
  const void* Wv  = d_in[9];
  const void* bv  = d_in[10];
  const void* Wih = d_in[11];
  const void* Whh = d_in[12];
  const void* bih = d_in[13];
  const void* bhh = d_in[14];
  float* ws = (float*)d_ws;

  // zero the atomic accumulators (SKC, SKX, RX)
  hipMemsetAsync(ws, 0, ZERO_FLOATS * sizeof(float), stream);

  k0_probe<<<1, 256, 0, stream>>>(cp, ws);
  k1_kbeta<<<NB, 256, 0, stream>>>(hop, Wk, bk, Wb, bb, ws);
  k2_score<<<dim3(16, NB), 256, 0, stream>>>(cp, cx, ws);
  k3a_wbias<<<NB, 256, 0, stream>>>(ws);
  k3b_gates<<<dim3(NB, 4), 576, 0, stream>>>(hop, Wih, Whh, bih, bhh, ws);
  k3c_combine<<<NB, 576, 0, stream>>>(hop, We, be, Wv, bv, ws, d_out);
  k4_cnew<<<dim3(32, NB), 256, 0, stream>>>(cp, ws, d_out);
}

// Round 2
// 617.321 us; speedup vs baseline: 1.6742x; 1.0853x over previous
//
#include <hip/hip_runtime.h>
#include <hip/hip_bf16.h>
#include <math.h>

#define NB 64
#define C1n 4096
#define C2n 128
#define DIMH 512
#define HIDN 516
#define INPN 132
#define GR   1548   // 3*HIDN gate rows
#define EPSF 1e-8f

typedef __hip_bfloat16 bf16;

// workspace layout (float offsets)
enum : size_t {
  OFF_SKC = 0,          // 64   (zero-init)
  OFF_SKX = 64,         // 64   (zero-init)
  OFF_RX  = 128,        // 8192 (zero-init)
  ZERO_FLOATS = 8320,   // memset range
  OFF_K   = 8320,       // 8192
  OFF_INVNK = 16512,    // 64
  OFF_BETA  = 16576,    // 64
  OFF_FLAG  = 16640,    // 64 (probe: 1.0 => inputs are f32, 0.0 => bf16)
  OFF_EKC = 16704,      // 262144
  OFF_EKX = 278848,     // 262144
  OFF_WB  = 540992,     // 1048576 (w_bias, [n][c][4])
  OFF_RB  = 1589568,    // 256
  OFF_SR  = 1589824,    // 33024  TRANSPOSED: [row][n]
  OFF_SZ  = 1622848,    // 33024  [row][n]
  OFF_SNI = 1655872,    // 33024  [row][n]
  OFF_SNH = 1688896,    // 33024  [row][n]
  OFF_E   = 1721920,    // 8192
  OFF_V   = 1730112,    // 8192
  OFF_HOB = 1738304,    // 256
  WS_FLOATS = 1738560   // ~6.95 MB
};

__device__ __forceinline__ float ldf(const void* p, size_t i, int f){
  if(f) return ((const float*)p)[i];
  return __bfloat162float(((const bf16*)p)[i]);
}
__device__ __forceinline__ void stf(void* p, size_t i, float v, int f){
  if(f) ((float*)p)[i] = v;
  else  ((bf16*)p)[i] = __float2bfloat16(v);
}
// vectorized 4-element load/store (ei must be a multiple of 4)
__device__ __forceinline__ float4 ld4(const void* p, size_t ei, int f){
  if(f) return ((const float4*)p)[ei >> 2];
  union { ushort4 u; bf16 h[4]; } t;
  t.u = ((const ushort4*)p)[ei >> 2];
  return make_float4(__bfloat162float(t.h[0]), __bfloat162float(t.h[1]),
                     __bfloat162float(t.h[2]), __bfloat162float(t.h[3]));
}
__device__ __forceinline__ void st4(void* p, size_t ei, float4 v, int f){
  if(f){ ((float4*)p)[ei >> 2] = v; return; }
  union { ushort4 u; bf16 h[4]; } t;
  t.h[0] = __float2bfloat16(v.x); t.h[1] = __float2bfloat16(v.y);
  t.h[2] = __float2bfloat16(v.z); t.h[3] = __float2bfloat16(v.w);
  ((ushort4*)p)[ei >> 2] = t.u;
}
__device__ __forceinline__ float expc(float x){
  return expf(fminf(fmaxf(x, -60.f), 60.f));
}

// ---------------- K0: dtype probe ----------------
__global__ void k0_probe(const void* cp, float* __restrict__ ws){
  int t = threadIdx.x; // 256
  __shared__ float red[256];
  const bf16* p = (const bf16*)cp;
  float m = 0.f;
  for(int i = t; i < 8192; i += 256){
    float v = __bfloat162float(p[i]);
    if(v != v) v = 1e30f;           // NaN -> huge
    m = fmaxf(m, fabsf(v));
  }
  red[t] = m;
  __syncthreads();
  for(int s = 128; s; s >>= 1){
    if(t < s) red[t] = fmaxf(red[t], red[t + s]);
    __syncthreads();
  }
  if(t == 0) ws[OFF_FLAG] = (red[0] > 1e4f) ? 1.0f : 0.0f;
}

// ---------------- K1: k = origin_h @ Wk^T + bk ; beta ; 1/||k|| ----------------
__global__ void k1_kbeta(const void* hop, const void* Wk, const void* bk,
                         const void* Wb, const void* bb, float* __restrict__ ws){
  int n = blockIdx.x;
  int t = threadIdx.x; // 256
  int f = (ws[OFF_FLAG] != 0.f);
  __shared__ float h[DIMH];
  __shared__ float kk[C2n];
  for(int d = t; d < DIMH; d += 256) h[d] = ldf(hop, (size_t)n*HIDN + d, f);
  __syncthreads();
  if(t < C2n){
    float acc = 0.f;
    for(int d = 0; d < DIMH; d += 4){
      float4 w = ld4(Wk, (size_t)t*DIMH + d, f);
      acc += w.x*h[d] + w.y*h[d+1] + w.z*h[d+2] + w.w*h[d+3];
    }
    acc += ldf(bk, t, f);
    kk[t] = acc;
    ws[OFF_K + n*C2n + t] = acc;
  } else if(t == 128){
    float acc = 0.f;
    for(int d = 0; d < DIMH; d += 4){
      float4 w = ld4(Wb, d, f);
      acc += w.x*h[d] + w.y*h[d+1] + w.z*h[d+2] + w.w*h[d+3];
    }
    acc += ldf(bb, 0, f);
    float sp = fmaxf(acc, 0.f) + log1pf(expc(-fabsf(acc)));  // softplus
    ws[OFF_BETA + n] = sp + 1.0f;
  }
  __syncthreads();
  if(t == 0){
    float s = 0.f;
    for(int c = 0; c < C2n; ++c) s += kk[c]*kk[c];
    ws[OFF_INVNK + n] = 1.0f / fmaxf(sqrtf(s), EPSF);
  }
}

// ---------------- K2: cos-sims, exp weights, sums, fused rx accumulation ----------
__global__ void k2_score(const void* cp, const void* cx, float* __restrict__ ws){
  int n = blockIdx.y;
  int cbase = blockIdx.x * 256;   // grid.x = 16
  int t = threadIdx.x;            // 256 = 4 waves
  int f = (ws[OFF_FLAG] != 0.f);
  int wave = t >> 6;
  int lane = t & 63;
  int half = lane >> 5;           // half-wave id within wave
  int l = lane & 31;              // lane within half

  // k fragment in registers: lane l covers d = 4l..4l+3
  float k0 = ws[OFF_K + n*C2n + l*4 + 0];
  float k1 = ws[OFF_K + n*C2n + l*4 + 1];
  float k2 = ws[OFF_K + n*C2n + l*4 + 2];
  float k3 = ws[OFF_K + n*C2n + l*4 + 3];
  float beta  = ws[OFF_BETA + n];
  float invnk = ws[OFF_INVNK + n];

  float sA = 0.f, sB = 0.f;
  float r0 = 0.f, r1 = 0.f, r2 = 0.f, r3 = 0.f;

  for(int it = 0; it < 32; ++it){
    int row = cbase + it*8 + wave*2 + half;   // 8 consecutive rows / block-iter
    size_t base = ((size_t)n*C1n + row)*C2n + l*4;
    float4 a = ld4(cp, base, f);
    float4 b = ld4(cx, base, f);

    float dc = a.x*k0 + a.y*k1 + a.z*k2 + a.w*k3;
    float nc = a.x*a.x + a.y*a.y + a.z*a.z + a.w*a.w;
    float dx = b.x*k0 + b.y*k1 + b.z*k2 + b.w*k3;
    float nx = b.x*b.x + b.y*b.y + b.z*b.z + b.w*b.w;
    #pragma unroll
    for(int m = 1; m < 32; m <<= 1){
      dc += __shfl_xor(dc, m, 64);
      nc += __shfl_xor(nc, m, 64);
      dx += __shfl_xor(dx, m, 64);
      nx += __shfl_xor(nx, m, 64);
    }
    float skc = dc / fmaxf(sqrtf(nc), EPSF) * invnk;
    float skx = dx / fmaxf(sqrtf(nx), EPSF) * invnk;
    float ekc = expc(skc * beta);
    float ekx = expc(skx * beta);
    if(l == 0){
      ws[OFF_EKC + (size_t)n*C1n + row] = ekc;
      ws[OFF_EKX + (size_t)n*C1n + row] = ekx;
    }
    sA += ekc; sB += ekx;
    r0 += ekx*b.x; r1 += ekx*b.y; r2 += ekx*b.z; r3 += ekx*b.w;
  }

  r0 += __shfl_xor(r0, 32, 64);
  r1 += __shfl_xor(r1, 32, 64);
  r2 += __shfl_xor(r2, 32, 64);
  r3 += __shfl_xor(r3, 32, 64);
  sA += __shfl_xor(sA, 32, 64);
  sB += __shfl_xor(sB, 32, 64);

  __shared__ float rxw[4][C2n];
  __shared__ float sred[8];
  if(lane < 32){
    rxw[wave][l*4 + 0] = r0; rxw[wave][l*4 + 1] = r1;
    rxw[wave][l*4 + 2] = r2; rxw[wave][l*4 + 3] = r3;
  }
  if(lane == 0){ sred[wave] = sA; sred[4 + wave] = sB; }
  __syncthreads();
  if(t < C2n)
    atomicAdd(&ws[OFF_RX + n*C2n + t],
              rxw[0][t] + rxw[1][t] + rxw[2][t] + rxw[3][t]);
  if(t == 0) atomicAdd(&ws[OFF_SKC + n], sred[0]+sred[1]+sred[2]+sred[3]);
  if(t == 1) atomicAdd(&ws[OFF_SKX + n], sred[4]+sred[5]+sred[6]+sred[7]);
}

// ---------------- K3a: w_bias (roll + softmax over 4 shifts), rb ----------------
__global__ void k3a_wbias(float* __restrict__ ws){
  int n = blockIdx.x;
  int t = threadIdx.x; // 256
  __shared__ float wl[C1n]; // 16KB
  __shared__ float r0[256], r1[256], r2[256], r3[256];
  float invSc = 1.0f / fmaxf(ws[OFF_SKC + n], 1e-30f);
  float invSx = 1.0f / fmaxf(ws[OFF_SKX + n], 1e-30f);
  for(int c = t; c < C1n; c += 256) wl[c] = ws[OFF_EKC + n*C1n + c] * invSc;
  __syncthreads();
  float a0=0.f, a1=0.f, a2=0.f, a3=0.f;
  for(int c = t; c < C1n; c += 256){
    int x = c >> 6, y = c & 63;
    float w0 = wl[ (x << 6)            | ((y-1) & 63) ];
    float w1 = wl[ (((x-1) & 63) << 6) | y            ];
    float w2 = wl[ (x << 6)            | ((y+1) & 63) ];
    float w3 = wl[ (((x+1) & 63) << 6) | y            ];
    float m = fmaxf(fmaxf(w0,w1), fmaxf(w2,w3));
    float e0 = expc(w0-m), e1 = expc(w1-m), e2 = expc(w2-m), e3 = expc(w3-m);
    float inv = 1.0f/(e0+e1+e2+e3);
    e0 *= inv; e1 *= inv; e2 *= inv; e3 *= inv;
    size_t wb = OFF_WB + ((size_t)n*C1n + c)*4;
    ws[wb] = e0; ws[wb+1] = e1; ws[wb+2] = e2; ws[wb+3] = e3;
    float wx = ws[OFF_EKX + n*C1n + c] * invSx;
    a0 += wx*e0; a1 += wx*e1; a2 += wx*e2; a3 += wx*e3;
  }
  r0[t]=a0; r1[t]=a1; r2[t]=a2; r3[t]=a3;
  __syncthreads();
  for(int s = 128; s; s >>= 1){
    if(t < s){ r0[t]+=r0[t+s]; r1[t]+=r1[t+s]; r2[t]+=r2[t+s]; r3[t]+=r3[t+s]; }
    __syncthreads();
  }
  if(t == 0){
    ws[OFF_RB + n*4 + 0] = r0[0]; ws[OFF_RB + n*4 + 1] = r1[0];
    ws[OFF_RB + n*4 + 2] = r2[0]; ws[OFF_RB + n*4 + 3] = r3[0];
  }
}

// ---------------- K3b: GRU gate GEMMs, lane=batch, rows partitioned ------------
// 64 lanes = 64 batch elements; each wave owns 8 output rows; weights streamed
// as wave-uniform float4 (each element read once on the whole GPU, amortized
// over 64 batches). X and H^T K-tiles staged transposed in LDS (conflict-free).
// Output stored TRANSPOSED [row][n] so stores coalesce.
__global__ void k3b_gates(const void* hop, const void* Wih, const void* Whh,
                          const void* bih, const void* bhh, float* __restrict__ ws){
  int t = threadIdx.x;       // 256 = 4 waves
  int wave = t >> 6, lane = t & 63;
  int row0 = blockIdx.x * 32 + wave * 8;
  int f = (ws[OFF_FLAG] != 0.f);

  __shared__ float sInv[64];
  __shared__ float Xs[INPN][64];   // 33.8 KB: Xs[d][n]
  __shared__ float Hs[64][64];     // 16.4 KB: K-tile of H^T

  if(t < 64) sInv[t] = 1.0f / fmaxf(ws[OFF_SKX + t], 1e-30f);
  __syncthreads();

  // stage X^T: x[n] = concat(rx[n]/skx[n], rb[n][0..3])
  for(int i = t; i < INPN*64; i += 256){
    int nn = i & 63, d = i >> 6;
    float v;
    if(d < C2n) v = ws[OFF_RX + nn*C2n + d] * sInv[nn];
    else        v = ws[OFF_RB + nn*4 + (d - C2n)];
    Xs[d][nn] = v;
  }
  __syncthreads();

  float acc_i[8], acc_h[8];
  #pragma unroll
  for(int r = 0; r < 8; ++r){ acc_i[r] = 0.f; acc_h[r] = 0.f; }

  bool active = (row0 < GR);
  int rclamp[8];
  #pragma unroll
  for(int r = 0; r < 8; ++r){
    int row = row0 + r;
    rclamp[r] = (row < GR) ? row : (GR - 1);
  }

  // phase 1: GI over X (K = 132)
  if(active){
    for(int d = 0; d < INPN; d += 4){
      float x0 = Xs[d][lane], x1 = Xs[d+1][lane];
      float x2 = Xs[d+2][lane], x3 = Xs[d+3][lane];
      #pragma unroll
      for(int r = 0; r < 8; ++r){
        float4 w = ld4(Wih, (size_t)rclamp[r]*INPN + d, f);
        acc_i[r] += w.x*x0 + w.y*x1 + w.z*x2 + w.w*x3;
      }
    }
  }

  // phase 2: GH over H (K = 516, tiled by 64)
  for(int kt = 0; kt < HIDN; kt += 64){
    int KT = (HIDN - kt < 64) ? (HIDN - kt) : 64;
    __syncthreads();
    for(int i = t; i < KT*64; i += 256){
      int nn = i & 63, dd = i >> 6;
      Hs[dd][nn] = ldf(hop, (size_t)nn*HIDN + kt + dd, f);
    }
    __syncthreads();
    if(active){
      for(int dd = 0; dd < KT; dd += 4){
        float x0 = Hs[dd][lane], x1 = Hs[dd+1][lane];
        float x2 = Hs[dd+2][lane], x3 = Hs[dd+3][lane];
        #pragma unroll
        for(int r = 0; r < 8; ++r){
          float4 w = ld4(Whh, (size_t)rclamp[r]*HIDN + kt + dd, f);
          acc_h[r] += w.x*x0 + w.y*x1 + w.z*x2 + w.w*x3;
        }
      }
    }
  }

  // writeback (transposed [row][n] -> coalesced)
  #pragma unroll
  for(int r = 0; r < 8; ++r){
    int row = row0 + r;
    if(row >= GR) break;
    float bi = ldf(bih, row, f), bh = ldf(bhh, row, f);
    if(row < HIDN){
      ws[OFF_SR + (size_t)row*64 + lane] = acc_i[r] + acc_h[r] + bi + bh;
    } else if(row < 2*HIDN){
      ws[OFF_SZ + (size_t)(row - HIDN)*64 + lane] = acc_i[r] + acc_h[r] + bi + bh;
    } else {
      ws[OFF_SNI + (size_t)(row - 2*HIDN)*64 + lane] = acc_i[r] + bi;
      ws[OFF_SNH + (size_t)(row - 2*HIDN)*64 + lane] = acc_h[r] + bh;
    }
  }
}

// ---------------- K3c: GRU combine, h_o out, h_o_bias, e, v ----------------
__global__ void k3c_combine(const void* hop, const void* We, const void* be,
                            const void* Wv, const void* bv,
                            float* __restrict__ ws, void* out){
  int n = blockIdx.x;
  int t = threadIdx.x; // 576
  int f = (ws[OFF_FLAG] != 0.f);
  __shared__ float ho[HIDN];
  if(t < HIDN){
    float sr = ws[OFF_SR  + (size_t)t*64 + n];
    float sz = ws[OFF_SZ  + (size_t)t*64 + n];
    float si = ws[OFF_SNI + (size_t)t*64 + n];
    float sh = ws[OFF_SNH + (size_t)t*64 + n];
    float rg = 1.0f/(1.0f + expc(-sr));
    float zg = 1.0f/(1.0f + expc(-sz));
    float ng = tanhf(si + rg*sh);
    float hv = ldf(hop, (size_t)n*HIDN + t, f);
    float o = (1.0f - zg)*ng + zg*hv;
    ho[t] = o;
    stf(out, (size_t)n*HIDN + t, o, f);
  }
  __syncthreads();
  if(t == 0){
    float a = ho[512], b = ho[513], c = ho[514], d2 = ho[515];
    float m = fmaxf(fmaxf(a,b), fmaxf(c,d2));
    float e0 = expc(a-m), e1 = expc(b-m), e2 = expc(c-m), e3 = expc(d2-m);
    float inv = 1.0f/(e0+e1+e2+e3);
    ws[OFF_HOB + n*4 + 0] = e0*inv; ws[OFF_HOB + n*4 + 1] = e1*inv;
    ws[OFF_HOB + n*4 + 2] = e2*inv; ws[OFF_HOB + n*4 + 3] = e3*inv;
  }
  if(t < 256){
    int c2 = t & 127, sel = t >> 7;
    const void* W = sel ? Wv : We;
    float acc = 0.f;
    for(int d = 0; d < DIMH; d += 4){
      float4 w = ld4(W, (size_t)c2*DIMH + d, f);
      acc += w.x*ho[d] + w.y*ho[d+1] + w.z*ho[d+2] + w.w*ho[d+3];
    }
    if(sel) ws[OFF_V + n*C2n + c2] = acc + ldf(bv, c2, f);
    else {
      float e = acc + ldf(be, c2, f);
      ws[OFF_E + n*C2n + c2] = 1.0f/(1.0f + expc(-e));
    }
  }
}

// ---------------- K4: c_new = c_prev*(1 - w_kc*e) + w_write*v (float4) ----------
__global__ void k4_cnew(const void* cp, float* __restrict__ ws, void* out){
  int n = blockIdx.y;
  int cbase = blockIdx.x * 128;
  int t = threadIdx.x; // 256: 32 float4-lanes x 8 channels in flight
  int f = (ws[OFF_FLAG] != 0.f);
  int dq = t & 31, sub = t >> 5;
  int d0 = dq * 4;
  float invSc = 1.0f / fmaxf(ws[OFF_SKC + n], 1e-30f);
  float4 ed = *(const float4*)&ws[OFF_E + n*C2n + d0];
  float4 vd = *(const float4*)&ws[OFF_V + n*C2n + d0];
  float h0 = ws[OFF_HOB + n*4 + 0], h1 = ws[OFF_HOB + n*4 + 1];
  float h2 = ws[OFF_HOB + n*4 + 2], h3 = ws[OFF_HOB + n*4 + 3];
  for(int i = 0; i < 16; ++i){
    int c = cbase + i*8 + sub;
    float wkc = ws[OFF_EKC + (size_t)n*C1n + c] * invSc;
    float4 wb4 = *(const float4*)&ws[OFF_WB + ((size_t)n*C1n + c)*4];
    float wwr = wb4.x*h0 + wb4.y*h1 + wb4.z*h2 + wb4.w*h3;
    size_t idx = ((size_t)n*C1n + c)*C2n + d0;
    float4 a = ld4(cp, idx, f);
    float4 o;
    o.x = a.x*(1.0f - wkc*ed.x) + wwr*vd.x;
    o.y = a.y*(1.0f - wkc*ed.y) + wwr*vd.y;
    o.z = a.z*(1.0f - wkc*ed.z) + wwr*vd.z;
    o.w = a.w*(1.0f - wkc*ed.w) + wwr*vd.w;
    st4(out, (size_t)(NB*HIDN) + idx, o, f);
  }
}

extern "C" void kernel_launch(void* const* d_in, const int* in_sizes, int n_in,
                              void* d_out, int out_size, void* d_ws, size_t ws_size,
                              hipStream_t stream){
  const void* hop = d_in[0];
  const void* cp  = d_in[1];
  const void* cx  = d_in[2];
  const void* Wk  = d_in[3];
  const void* bk  = d_in[4];
  const void* Wb  = d_in[5];
  const void* bb  = d_in[6];
  const void* We  = d_in[7];
  const void* be  = d_in[8];
  const void* Wv  = d_in[9];
  const void* bv  = d_in[10];
  const void* Wih = d_in[11];
  const void* Whh = d_in[12];
  const void* bih = d_in[13];
  const void* bhh = d_in[14];
  float* ws = (float*)d_ws;

  // zero the atomic accumulators (SKC, SKX, RX)
  hipMemsetAsync(ws, 0, ZERO_FLOATS * sizeof(float), stream);

  k0_probe<<<1, 256, 0, stream>>>(cp, ws);
  k1_kbeta<<<NB, 256, 0, stream>>>(hop, Wk, bk, Wb, bb, ws);
  k2_score<<<dim3(16, NB), 256, 0, stream>>>(cp, cx, ws);
  k3a_wbias<<<NB, 256, 0, stream>>>(ws);
  k3b_gates<<<dim3((GR + 31) / 32), 256, 0, stream>>>(hop, Wih, Whh, bih, bhh, ws);
  k3c_combine<<<NB, 576, 0, stream>>>(hop, We, be, Wv, bv, ws, d_out);
  k4_cnew<<<dim3(32, NB), 256, 0, stream>>>(cp, ws, d_out);
}

// Round 3
// 478.875 us; speedup vs baseline: 2.1582x; 1.2891x over previous
//
#include <hip/hip_runtime.h>
#include <hip/hip_bf16.h>
#include <math.h>

#define NB 64
#define C1n 4096
#define C2n 128
#define DIMH 512
#define HIDN 516
#define INPN 132
#define GR   1548   // 3*HIDN gate rows
#define KTOT 648    // INPN + HIDN
#define EPSF 1e-8f

typedef __hip_bfloat16 bf16;

// workspace layout (float offsets)
enum : size_t {
  OFF_SKC = 0,          // 64   (zero-init)
  OFF_SKX = 64,         // 64   (zero-init)
  OFF_RX  = 128,        // 8192 (zero-init)
  ZERO_FLOATS = 8320,   // memset range #1
  OFF_K   = 8320,       // 8192
  OFF_INVNK = 16512,    // 64
  OFF_BETA  = 16576,    // 64
  OFF_FLAG  = 16640,    // 64 (probe: 1.0 => inputs are f32, 0.0 => bf16)
  OFF_EKC = 16704,      // 262144
  OFF_EKX = 278848,     // 262144 (dead after k3a -> reused as XH[648][64])
  OFF_XH  = 278848,     // alias of EKX
  OFF_WB  = 540992,     // 1048576 (w_bias, [n][c][4])
  OFF_RB  = 1589568,    // 256
  OFF_SR  = 1589824,    // 33024  TRANSPOSED: [row][n]  (zero-init, memset #2)
  OFF_SZ  = 1622848,    // 33024  [row][n]
  OFF_SNI = 1655872,    // 33024  [row][n]
  OFF_SNH = 1688896,    // 33024  [row][n]
  GATE_FLOATS = 132096, // memset range #2 (SR..SNH)
  OFF_E   = 1721920,    // 8192
  OFF_V   = 1730112,    // 8192
  OFF_HOB = 1738304,    // 256
  WS_FLOATS = 1738560   // ~6.95 MB
};

__device__ __forceinline__ float ldf(const void* p, size_t i, int f){
  if(f) return ((const float*)p)[i];
  return __bfloat162float(((const bf16*)p)[i]);
}
__device__ __forceinline__ void stf(void* p, size_t i, float v, int f){
  if(f) ((float*)p)[i] = v;
  else  ((bf16*)p)[i] = __float2bfloat16(v);
}
// vectorized 4-element load/store (ei must be a multiple of 4)
__device__ __forceinline__ float4 ld4(const void* p, size_t ei, int f){
  if(f) return ((const float4*)p)[ei >> 2];
  union { ushort4 u; bf16 h[4]; } t;
  t.u = ((const ushort4*)p)[ei >> 2];
  return make_float4(__bfloat162float(t.h[0]), __bfloat162float(t.h[1]),
                     __bfloat162float(t.h[2]), __bfloat162float(t.h[3]));
}
__device__ __forceinline__ void st4(void* p, size_t ei, float4 v, int f){
  if(f){ ((float4*)p)[ei >> 2] = v; return; }
  union { ushort4 u; bf16 h[4]; } t;
  t.h[0] = __float2bfloat16(v.x); t.h[1] = __float2bfloat16(v.y);
  t.h[2] = __float2bfloat16(v.z); t.h[3] = __float2bfloat16(v.w);
  ((ushort4*)p)[ei >> 2] = t.u;
}
__device__ __forceinline__ float expc(float x){
  return expf(fminf(fmaxf(x, -60.f), 60.f));
}

// ---------------- K0: dtype probe ----------------
__global__ void k0_probe(const void* cp, float* __restrict__ ws){
  int t = threadIdx.x; // 256
  __shared__ float red[256];
  const bf16* p = (const bf16*)cp;
  float m = 0.f;
  for(int i = t; i < 8192; i += 256){
    float v = __bfloat162float(p[i]);
    if(v != v) v = 1e30f;           // NaN -> huge
    m = fmaxf(m, fabsf(v));
  }
  red[t] = m;
  __syncthreads();
  for(int s = 128; s; s >>= 1){
    if(t < s) red[t] = fmaxf(red[t], red[t + s]);
    __syncthreads();
  }
  if(t == 0) ws[OFF_FLAG] = (red[0] > 1e4f) ? 1.0f : 0.0f;
}

// ---------------- K1: k = origin_h @ Wk^T + bk ; beta ; 1/||k|| ----------------
__global__ void k1_kbeta(const void* hop, const void* Wk, const void* bk,
                         const void* Wb, const void* bb, float* __restrict__ ws){
  int n = blockIdx.x;
  int t = threadIdx.x; // 256
  int f = (ws[OFF_FLAG] != 0.f);
  __shared__ float h[DIMH];
  __shared__ float kk[C2n];
  for(int d = t; d < DIMH; d += 256) h[d] = ldf(hop, (size_t)n*HIDN + d, f);
  __syncthreads();
  if(t < C2n){
    float acc = 0.f;
    for(int d = 0; d < DIMH; d += 4){
      float4 w = ld4(Wk, (size_t)t*DIMH + d, f);
      acc += w.x*h[d] + w.y*h[d+1] + w.z*h[d+2] + w.w*h[d+3];
    }
    acc += ldf(bk, t, f);
    kk[t] = acc;
    ws[OFF_K + n*C2n + t] = acc;
  } else if(t == 128){
    float acc = 0.f;
    for(int d = 0; d < DIMH; d += 4){
      float4 w = ld4(Wb, d, f);
      acc += w.x*h[d] + w.y*h[d+1] + w.z*h[d+2] + w.w*h[d+3];
    }
    acc += ldf(bb, 0, f);
    float sp = fmaxf(acc, 0.f) + log1pf(expc(-fabsf(acc)));  // softplus
    ws[OFF_BETA + n] = sp + 1.0f;
  }
  __syncthreads();
  if(t == 0){
    float s = 0.f;
    for(int c = 0; c < C2n; ++c) s += kk[c]*kk[c];
    ws[OFF_INVNK + n] = 1.0f / fmaxf(sqrtf(s), EPSF);
  }
}

// ---------------- K2: cos-sims, exp weights, sums, fused rx accumulation ----------
__global__ void k2_score(const void* cp, const void* cx, float* __restrict__ ws){
  int n = blockIdx.y;
  int cbase = blockIdx.x * 256;   // grid.x = 16
  int t = threadIdx.x;            // 256 = 4 waves
  int f = (ws[OFF_FLAG] != 0.f);
  int wave = t >> 6;
  int lane = t & 63;
  int half = lane >> 5;           // half-wave id within wave
  int l = lane & 31;              // lane within half

  // k fragment in registers: lane l covers d = 4l..4l+3
  float k0 = ws[OFF_K + n*C2n + l*4 + 0];
  float k1 = ws[OFF_K + n*C2n + l*4 + 1];
  float k2 = ws[OFF_K + n*C2n + l*4 + 2];
  float k3 = ws[OFF_K + n*C2n + l*4 + 3];
  float beta  = ws[OFF_BETA + n];
  float invnk = ws[OFF_INVNK + n];

  float sA = 0.f, sB = 0.f;
  float r0 = 0.f, r1 = 0.f, r2 = 0.f, r3 = 0.f;

  for(int it = 0; it < 32; ++it){
    int row = cbase + it*8 + wave*2 + half;   // 8 consecutive rows / block-iter
    size_t base = ((size_t)n*C1n + row)*C2n + l*4;
    float4 a = ld4(cp, base, f);
    float4 b = ld4(cx, base, f);

    float dc = a.x*k0 + a.y*k1 + a.z*k2 + a.w*k3;
    float nc = a.x*a.x + a.y*a.y + a.z*a.z + a.w*a.w;
    float dx = b.x*k0 + b.y*k1 + b.z*k2 + b.w*k3;
    float nx = b.x*b.x + b.y*b.y + b.z*b.z + b.w*b.w;
    #pragma unroll
    for(int m = 1; m < 32; m <<= 1){
      dc += __shfl_xor(dc, m, 64);
      nc += __shfl_xor(nc, m, 64);
      dx += __shfl_xor(dx, m, 64);
      nx += __shfl_xor(nx, m, 64);
    }
    float skc = dc / fmaxf(sqrtf(nc), EPSF) * invnk;
    float skx = dx / fmaxf(sqrtf(nx), EPSF) * invnk;
    float ekc = expc(skc * beta);
    float ekx = expc(skx * beta);
    if(l == 0){
      ws[OFF_EKC + (size_t)n*C1n + row] = ekc;
      ws[OFF_EKX + (size_t)n*C1n + row] = ekx;
    }
    sA += ekc; sB += ekx;
    r0 += ekx*b.x; r1 += ekx*b.y; r2 += ekx*b.z; r3 += ekx*b.w;
  }

  r0 += __shfl_xor(r0, 32, 64);
  r1 += __shfl_xor(r1, 32, 64);
  r2 += __shfl_xor(r2, 32, 64);
  r3 += __shfl_xor(r3, 32, 64);
  sA += __shfl_xor(sA, 32, 64);
  sB += __shfl_xor(sB, 32, 64);

  __shared__ float rxw[4][C2n];
  __shared__ float sred[8];
  if(lane < 32){
    rxw[wave][l*4 + 0] = r0; rxw[wave][l*4 + 1] = r1;
    rxw[wave][l*4 + 2] = r2; rxw[wave][l*4 + 3] = r3;
  }
  if(lane == 0){ sred[wave] = sA; sred[4 + wave] = sB; }
  __syncthreads();
  if(t < C2n)
    atomicAdd(&ws[OFF_RX + n*C2n + t],
              rxw[0][t] + rxw[1][t] + rxw[2][t] + rxw[3][t]);
  if(t == 0) atomicAdd(&ws[OFF_SKC + n], sred[0]+sred[1]+sred[2]+sred[3]);
  if(t == 1) atomicAdd(&ws[OFF_SKX + n], sred[4]+sred[5]+sred[6]+sred[7]);
}

// ---------------- K3a: w_bias (roll + softmax over 4 shifts), rb ----------------
__global__ void k3a_wbias(float* __restrict__ ws){
  int n = blockIdx.x;
  int t = threadIdx.x; // 256
  __shared__ float wl[C1n]; // 16KB
  __shared__ float r0[256], r1[256], r2[256], r3[256];
  float invSc = 1.0f / fmaxf(ws[OFF_SKC + n], 1e-30f);
  float invSx = 1.0f / fmaxf(ws[OFF_SKX + n], 1e-30f);
  for(int c = t; c < C1n; c += 256) wl[c] = ws[OFF_EKC + n*C1n + c] * invSc;
  __syncthreads();
  float a0=0.f, a1=0.f, a2=0.f, a3=0.f;
  for(int c = t; c < C1n; c += 256){
    int x = c >> 6, y = c & 63;
    float w0 = wl[ (x << 6)            | ((y-1) & 63) ];
    float w1 = wl[ (((x-1) & 63) << 6) | y            ];
    float w2 = wl[ (x << 6)            | ((y+1) & 63) ];
    float w3 = wl[ (((x+1) & 63) << 6) | y            ];
    float m = fmaxf(fmaxf(w0,w1), fmaxf(w2,w3));
    float e0 = expc(w0-m), e1 = expc(w1-m), e2 = expc(w2-m), e3 = expc(w3-m);
    float inv = 1.0f/(e0+e1+e2+e3);
    e0 *= inv; e1 *= inv; e2 *= inv; e3 *= inv;
    size_t wb = OFF_WB + ((size_t)n*C1n + c)*4;
    ws[wb] = e0; ws[wb+1] = e1; ws[wb+2] = e2; ws[wb+3] = e3;
    float wx = ws[OFF_EKX + n*C1n + c] * invSx;
    a0 += wx*e0; a1 += wx*e1; a2 += wx*e2; a3 += wx*e3;
  }
  r0[t]=a0; r1[t]=a1; r2[t]=a2; r3[t]=a3;
  __syncthreads();
  for(int s = 128; s; s >>= 1){
    if(t < s){ r0[t]+=r0[t+s]; r1[t]+=r1[t+s]; r2[t]+=r2[t+s]; r3[t]+=r3[t+s]; }
    __syncthreads();
  }
  if(t == 0){
    ws[OFF_RB + n*4 + 0] = r0[0]; ws[OFF_RB + n*4 + 1] = r1[0];
    ws[OFF_RB + n*4 + 2] = r2[0]; ws[OFF_RB + n*4 + 3] = r3[0];
  }
}

// ---------------- K3x: pack XH[d][n] = concat(rx/skx, rb, h) -------------------
// Runs AFTER k3a (rb ready); overwrites the now-dead EKX region.
__global__ void k3x_pack(const void* hop, float* __restrict__ ws){
  int idx = blockIdx.x * 256 + threadIdx.x;   // grid 162 -> 41472 = 648*64
  int d = idx >> 6, n = idx & 63;
  int f = (ws[OFF_FLAG] != 0.f);
  float v;
  if(d < C2n)       v = ws[OFF_RX + n*C2n + d] / fmaxf(ws[OFF_SKX + n], 1e-30f);
  else if(d < INPN) v = ws[OFF_RB + n*4 + (d - C2n)];
  else              v = ldf(hop, (size_t)n*HIDN + (d - INPN), f);
  ws[OFF_XH + (size_t)d*64 + n] = v;
}

// ---------------- K3b: GRU gate GEMMs, row-split x K-split, atomic partials ----
// Grid (97, 5): y=0 -> X part (K=132, Wih); y=1..4 -> H chunks {132,128,128,128}
// (Whh). Block = 4 waves x 4 rows; lane = batch. Weights: wave-uniform float4
// (each element read once GPU-wide). XH: lane-coalesced from L2. No LDS, no
// barriers; 485 independent blocks hide latency by TLP. Biases added in k3c.
__global__ void k3b_gates(const void* Wih, const void* Whh, float* __restrict__ ws){
  int t = threadIdx.x;            // 256 = 4 waves
  int wave = t >> 6, lane = t & 63;
  int chunk = blockIdx.y;
  int row0 = blockIdx.x * 16 + wave * 4;
  int f = (ws[OFF_FLAG] != 0.f);

  int isX = (chunk == 0);
  int koff = isX ? 0 : ((chunk == 1) ? 0 : 132 + (chunk - 2) * 128);
  int klen = (chunk <= 1) ? 132 : 128;
  int kbase = isX ? koff : (INPN + koff);      // row into XH
  const void* W = isX ? Wih : Whh;
  size_t wstride = isX ? INPN : HIDN;

  int r4[4];
  #pragma unroll
  for(int r = 0; r < 4; ++r){
    int row = row0 + r;
    r4[r] = (row < GR) ? row : (GR - 1);
  }

  float acc[4] = {0.f, 0.f, 0.f, 0.f};
  for(int d = 0; d < klen; d += 4){
    float x0 = ws[OFF_XH + (size_t)(kbase + d    )*64 + lane];
    float x1 = ws[OFF_XH + (size_t)(kbase + d + 1)*64 + lane];
    float x2 = ws[OFF_XH + (size_t)(kbase + d + 2)*64 + lane];
    float x3 = ws[OFF_XH + (size_t)(kbase + d + 3)*64 + lane];
    #pragma unroll
    for(int r = 0; r < 4; ++r){
      float4 w = ld4(W, (size_t)r4[r]*wstride + koff + d, f);
      acc[r] += w.x*x0 + w.y*x1 + w.z*x2 + w.w*x3;
    }
  }

  #pragma unroll
  for(int r = 0; r < 4; ++r){
    int row = row0 + r;
    if(row >= GR) continue;
    size_t dst;
    if(row < HIDN)        dst = OFF_SR  + (size_t)row*64;
    else if(row < 2*HIDN) dst = OFF_SZ  + (size_t)(row - HIDN)*64;
    else                  dst = (isX ? OFF_SNI : OFF_SNH) + (size_t)(row - 2*HIDN)*64;
    atomicAdd(&ws[dst + lane], acc[r]);
  }
}

// ---------------- K3c: GRU combine (+biases), h_o out, h_o_bias, e, v ----------
__global__ void k3c_combine(const void* hop, const void* We, const void* be,
                            const void* Wv, const void* bv,
                            const void* bih, const void* bhh,
                            float* __restrict__ ws, void* out){
  int n = blockIdx.x;
  int t = threadIdx.x; // 576
  int f = (ws[OFF_FLAG] != 0.f);
  __shared__ float ho[HIDN];
  if(t < HIDN){
    float sr = ws[OFF_SR  + (size_t)t*64 + n] + ldf(bih, t, f) + ldf(bhh, t, f);
    float sz = ws[OFF_SZ  + (size_t)t*64 + n] + ldf(bih, HIDN + t, f) + ldf(bhh, HIDN + t, f);
    float si = ws[OFF_SNI + (size_t)t*64 + n] + ldf(bih, 2*HIDN + t, f);
    float sh = ws[OFF_SNH + (size_t)t*64 + n] + ldf(bhh, 2*HIDN + t, f);
    float rg = 1.0f/(1.0f + expc(-sr));
    float zg = 1.0f/(1.0f + expc(-sz));
    float ng = tanhf(si + rg*sh);
    float hv = ldf(hop, (size_t)n*HIDN + t, f);
    float o = (1.0f - zg)*ng + zg*hv;
    ho[t] = o;
    stf(out, (size_t)n*HIDN + t, o, f);
  }
  __syncthreads();
  if(t == 0){
    float a = ho[512], b = ho[513], c = ho[514], d2 = ho[515];
    float m = fmaxf(fmaxf(a,b), fmaxf(c,d2));
    float e0 = expc(a-m), e1 = expc(b-m), e2 = expc(c-m), e3 = expc(d2-m);
    float inv = 1.0f/(e0+e1+e2+e3);
    ws[OFF_HOB + n*4 + 0] = e0*inv; ws[OFF_HOB + n*4 + 1] = e1*inv;
    ws[OFF_HOB + n*4 + 2] = e2*inv; ws[OFF_HOB + n*4 + 3] = e3*inv;
  }
  if(t < 256){
    int c2 = t & 127, sel = t >> 7;
    const void* W = sel ? Wv : We;
    float acc = 0.f;
    for(int d = 0; d < DIMH; d += 4){
      float4 w = ld4(W, (size_t)c2*DIMH + d, f);
      acc += w.x*ho[d] + w.y*ho[d+1] + w.z*ho[d+2] + w.w*ho[d+3];
    }
    if(sel) ws[OFF_V + n*C2n + c2] = acc + ldf(bv, c2, f);
    else {
      float e = acc + ldf(be, c2, f);
      ws[OFF_E + n*C2n + c2] = 1.0f/(1.0f + expc(-e));
    }
  }
}

// ---------------- K4: c_new = c_prev*(1 - w_kc*e) + w_write*v (float4) ----------
__global__ void k4_cnew(const void* cp, float* __restrict__ ws, void* out){
  int n = blockIdx.y;
  int cbase = blockIdx.x * 128;
  int t = threadIdx.x; // 256: 32 float4-lanes x 8 channels in flight
  int f = (ws[OFF_FLAG] != 0.f);
  int dq = t & 31, sub = t >> 5;
  int d0 = dq * 4;
  float invSc = 1.0f / fmaxf(ws[OFF_SKC + n], 1e-30f);
  float4 ed = *(const float4*)&ws[OFF_E + n*C2n + d0];
  float4 vd = *(const float4*)&ws[OFF_V + n*C2n + d0];
  float h0 = ws[OFF_HOB + n*4 + 0], h1 = ws[OFF_HOB + n*4 + 1];
  float h2 = ws[OFF_HOB + n*4 + 2], h3 = ws[OFF_HOB + n*4 + 3];
  for(int i = 0; i < 16; ++i){
    int c = cbase + i*8 + sub;
    float wkc = ws[OFF_EKC + (size_t)n*C1n + c] * invSc;
    float4 wb4 = *(const float4*)&ws[OFF_WB + ((size_t)n*C1n + c)*4];
    float wwr = wb4.x*h0 + wb4.y*h1 + wb4.z*h2 + wb4.w*h3;
    size_t idx = ((size_t)n*C1n + c)*C2n + d0;
    float4 a = ld4(cp, idx, f);
    float4 o;
    o.x = a.x*(1.0f - wkc*ed.x) + wwr*vd.x;
    o.y = a.y*(1.0f - wkc*ed.y) + wwr*vd.y;
    o.z = a.z*(1.0f - wkc*ed.z) + wwr*vd.z;
    o.w = a.w*(1.0f - wkc*ed.w) + wwr*vd.w;
    st4(out, (size_t)(NB*HIDN) + idx, o, f);
  }
}

extern "C" void kernel_launch(void* const* d_in, const int* in_sizes, int n_in,
                              void* d_out, int out_size, void* d_ws, size_t ws_size,
                              hipStream_t stream){
  const void* hop = d_in[0];
  const void* cp  = d_in[1];
  const void* cx  = d_in[2];
  const void* Wk  = d_in[3];
  const void* bk  = d_in[4];
  const void* Wb  = d_in[5];
  const void* bb  = d_in[6];
  const void* We  = d_in[7];
  const void* be  = d_in[8];
  const void* Wv  = d_in[9];
  const void* bv  = d_in[10];
  const void* Wih = d_in[11];
  const void* Whh = d_in[12];
  const void* bih = d_in[13];
  const void* bhh = d_in[14];
  float* ws = (float*)d_ws;

  // zero the atomic accumulators (SKC, SKX, RX) and the gate partial buffers
  hipMemsetAsync(ws, 0, ZERO_FLOATS * sizeof(float), stream);
  hipMemsetAsync(ws + OFF_SR, 0, GATE_FLOATS * sizeof(float), stream);

  k0_probe<<<1, 256, 0, stream>>>(cp, ws);
  k1_kbeta<<<NB, 256, 0, stream>>>(hop, Wk, bk, Wb, bb, ws);
  k2_score<<<dim3(16, NB), 256, 0, stream>>>(cp, cx, ws);
  k3a_wbias<<<NB, 256, 0, stream>>>(ws);
  k3x_pack<<<162, 256, 0, stream>>>(hop, ws);
  k3b_gates<<<dim3((GR + 15) / 16, 5), 256, 0, stream>>>(Wih, Whh, ws);
  k3c_combine<<<NB, 576, 0, stream>>>(hop, We, be, Wv, bv, bih, bhh, ws, d_out);
  k4_cnew<<<dim3(32, NB), 256, 0, stream>>>(cp, ws, d_out);
}